// Round 1
// baseline (2938.005 us; speedup 1.0000x reference)
//
#include <hip/hip_runtime.h>
#include <math.h>

// ExactContinuousSBM: reverse VP-SDE sampling of a Gaussian mixture.
// B=8192 trajectories are fully independent -> one persistent kernel,
// x lives in registers across all 255 steps. Per-step shared constants
// (iv = 1/v, A = m*iv, const_k) are rebuilt in LDS each step per block.
//
// Layout: 512 blocks x 128 threads. 8 lanes per batch element (4 dims each),
// 16 b per block. D-reduction over the 8 lanes via DPP (VALU pipe).

namespace {

constexpr int BD   = 8192;   // batch
constexpr int DIMN = 32;     // dims
constexpr int KM   = 64;     // mixture components
constexpr int NST  = 255;    // EM steps
constexpr float TMINc = 1e-4f, TMAXc = 1.0f;
constexpr float BMIN = 0.1f,  BMAX = 20.0f;

// butterfly add with DPP; CTRL: 0xB1 = quad_perm [1,0,3,2] (xor1),
// 0x4E = quad_perm [2,3,0,1] (xor2), 0x141 = row_half_mirror (xor4-equivalent
// after the first two stages).
template <int CTRL>
__device__ __forceinline__ float dpp_addf(float v) {
  int other = __builtin_amdgcn_update_dpp(0, __float_as_int(v), CTRL, 0xf, 0xf, true);
  return v + __int_as_float(other);
}

__global__ __launch_bounds__(128) void sbm_kernel(
    const float* __restrict__ xin,    // [8192,32]
    const float* __restrict__ cen_g,  // [64,32]
    const float* __restrict__ std_g,  // [64,32]
    const float* __restrict__ w_g,    // [64]
    const float* __restrict__ noi,    // [255,8192,32]
    float* __restrict__ out)          // [8192,32]
{
  __shared__ __align__(16) float s_iv[KM][DIMN];  // 1/v
  __shared__ __align__(16) float s_a [KM][DIMN];  // m/v
  __shared__ float s_c[KM];                       // log w - 0.5*sum m^2/v - 16*sum log v

  const int tid = threadIdx.x;
  const int dc  = tid & 7;         // d-chunk: 4 dims
  const int bs  = tid >> 3;        // b-slot 0..15
  const int b   = blockIdx.x * 16 + bs;
  const int d0  = dc * 4;

  // const-gen assignment: each thread owns one k-half-row (16 dims)
  const int gk = tid >> 1;
  const int gd = (tid & 1) * 16;

  float cen[16], s2[16];
#pragma unroll
  for (int i = 0; i < 16; ++i) {
    cen[i] = cen_g[gk * DIMN + gd + i];
    float s = std_g[gk * DIMN + gd + i];
    s2[i] = s * s;
  }
  const float lw = __logf(w_g[gk]);

  float x[4];
#pragma unroll
  for (int i = 0; i < 4; ++i) x[i] = xin[b * DIMN + d0 + i];

#pragma unroll 1
  for (int j = 0; j < NST; ++j) {
    // reversed linspace(T_MIN, T_MAX, 256)
    const float t  = fmaf((float)(255 - j) * (1.0f / 255.0f), (TMAXc - TMINc), TMINc);
    const float tn = fmaf((float)(254 - j) * (1.0f / 255.0f), (TMAXc - TMINc), TMINc);
    const float dt = tn - t;                                   // negative
    const float bt = fmaf(BMAX - BMIN, t, BMIN);
    const float Bt = fmaf(0.5f * (BMAX - BMIN), t * t, BMIN * t);
    const float eB  = __expf(-Bt);
    const float om  = -expm1f(-Bt);                            // 1 - eB, accurately
    const float smB = sqrtf(eB);

    // prefetch this step's noise (overlaps const-gen + barrier)
    const float4 z = *reinterpret_cast<const float4*>(
        noi + ((size_t)j * BD + b) * (size_t)DIMN + d0);

    // ---- per-step shared constants ----
    float cq = 0.0f, c2 = 0.0f;
#pragma unroll
    for (int i = 0; i < 16; ++i) {
      float m  = smB * cen[i];
      float v  = fmaf(eB, s2[i], om);
      float iv = 1.0f / v;
      float A  = m * iv;
      s_iv[gk][gd + i] = iv;
      s_a [gk][gd + i] = A;
      cq = fmaf(m, A, cq);     // m^2/v
      c2 += __logf(v);
    }
    cq = dpp_addf<0xB1>(cq);   // pair-reduce over the two half-rows
    c2 = dpp_addf<0xB1>(c2);
    if ((tid & 1) == 0) s_c[gk] = lw - 0.5f * cq - 16.0f * c2;
    __syncthreads();

    // ---- online-softmax k-loop ----
    float h[4];
#pragma unroll
    for (int i = 0; i < 4; ++i) h[i] = -0.5f * x[i] * x[i];

    float M = -__builtin_inff();
    float L = 0.0f;
    float SIV[4] = {0.f, 0.f, 0.f, 0.f};   // sum e * iv
    float SA [4] = {0.f, 0.f, 0.f, 0.f};   // sum e * (m*iv)

#pragma unroll 8
    for (int k = 0; k < KM; ++k) {
      const float4 iv4 = *reinterpret_cast<const float4*>(&s_iv[k][d0]);
      const float4 a4  = *reinterpret_cast<const float4*>(&s_a[k][d0]);
      // lane-partial of logc: sum_d (x*A - 0.5*x^2*iv)
      float p = h[0] * iv4.x;
      p = fmaf(x[0], a4.x, p);
      p = fmaf(h[1], iv4.y, p);
      p = fmaf(x[1], a4.y, p);
      p = fmaf(h[2], iv4.z, p);
      p = fmaf(x[2], a4.z, p);
      p = fmaf(h[3], iv4.w, p);
      p = fmaf(x[3], a4.w, p);
      // full-D sum across the 8 lanes of this b (bitwise identical on all 8)
      p = dpp_addf<0xB1>(p);
      p = dpp_addf<0x4E>(p);
      p = dpp_addf<0x141>(p);
      const float lc = p + s_c[k];
      const float nM = fmaxf(M, lc);
      const float al = __expf(M - nM);   // 1.0 exactly when max unchanged
      const float e  = __expf(lc - nM);
      M = nM;
      L = fmaf(L, al, e);
      SIV[0] = fmaf(SIV[0], al, e * iv4.x);
      SIV[1] = fmaf(SIV[1], al, e * iv4.y);
      SIV[2] = fmaf(SIV[2], al, e * iv4.z);
      SIV[3] = fmaf(SIV[3], al, e * iv4.w);
      SA[0]  = fmaf(SA[0],  al, e * a4.x);
      SA[1]  = fmaf(SA[1],  al, e * a4.y);
      SA[2]  = fmaf(SA[2],  al, e * a4.z);
      SA[3]  = fmaf(SA[3],  al, e * a4.w);
    }

    // ---- Euler-Maruyama update ----
    // score_d = (SA - x*SIV)/L ; x' = x*(1 - 0.5*bt*dt) + (-bt*dt)*score + sqrt(bt)*sqrt(|dt|)*z
    const float invL = 1.0f / L;
    const float cA   = fmaf(-0.5f * bt, dt, 1.0f);
    const float cb2  = (-bt * dt) * invL;
    const float sq   = sqrtf(bt) * sqrtf(-dt);
    const float zc[4] = {z.x, z.y, z.z, z.w};
#pragma unroll
    for (int i = 0; i < 4; ++i) {
      float u = fmaf(-x[i], SIV[i], SA[i]);   // unnormalized (SA - x*SIV)
      float w = sq * zc[i];
      w = fmaf(cA, x[i], w);
      x[i] = fmaf(cb2, u, w);
    }
    __syncthreads();   // protect LDS before next step's const-gen overwrites
  }

#pragma unroll
  for (int i = 0; i < 4; ++i) out[b * DIMN + d0 + i] = x[i];
}

}  // namespace

extern "C" void kernel_launch(void* const* d_in, const int* in_sizes, int n_in,
                              void* d_out, int out_size, void* d_ws, size_t ws_size,
                              hipStream_t stream) {
  const float* x_init  = (const float*)d_in[0];
  const float* centers = (const float*)d_in[1];
  const float* stds    = (const float*)d_in[2];
  const float* weights = (const float*)d_in[3];
  const float* noise   = (const float*)d_in[4];
  float* out = (float*)d_out;

  sbm_kernel<<<dim3(512), dim3(128), 0, stream>>>(x_init, centers, stds, weights,
                                                  noise, out);
}